// Round 7
// baseline (240.076 us; speedup 1.0000x reference)
//
#include <hip/hip_runtime.h>
#include <hip/hip_fp16.h>

#define EPS 1e-5f

constexpr int B = 8;
constexpr int V = 100000;
constexpr int F = 200000;
constexpr int U = 1024;
constexpr int T = 110000;
constexpr int CAP = 24;                     // max faces/vertex (data max ~20)

constexpr int NBUK = (V + 127) / 128;       // 782 buckets, 128 vertices each
constexpr int N4   = (3 * F) / 4;           // 150000 int4 edge-quads
constexpr int EB   = (N4 + 255) / 256;      // 586 edge blocks
constexpr int TRB  = (V + 255) / 256;       // 391 transpose blocks

// Batch-per-XCD decomposition (batch = blockIdx%8 tracks the XCD round-robin;
// validated R6: per-XCD verts slices DID become L2-resident, FETCH dropped).
// R6's regression was scalar float3 gathers (9 divergent dword reqs/lane) +
// an extra fnT->fn transpose. Fix: per-batch float4 slices (1 aligned 16 B
// request per gather) and batch-major layouts end-to-end (no transposes).
constexpr int FCH  = (F + 255) / 256;       // 782 face chunks
constexpr int FNB2 = FCH * 8;               // 6256 FN blocks (chunk x batch)
constexpr int TQ   = 2;                     // samples per thread (corner role)
constexpr int CPB  = (T / TQ + 255) / 256;  // 215 blocks
constexpr int TCH  = (T + 255) / 256;       // 430 sample chunks (k6)
constexpr int VCH  = (V + 255) / 256;       // 391 vertex chunks (k7)

// packed half4 (8 B): x,y,z in halves, w pad
struct alignas(8) h4 { __half2 a, b; };
__device__ inline h4 pack_h4(float x, float y, float z) {
    h4 r; r.a = __floats2half2_rn(x, y); r.b = __floats2half2_rn(z, 0.0f);
    return r;
}
__device__ inline float3 unpack_h4(h4 v) {
    float2 xy = __half22float2(v.a);
    float2 zw = __half22float2(v.b);
    return make_float3(xy.x, xy.y, zw.x);
}

// 16 B corner record: 3x21-bit indices packed in (lo,hi) + half weights
struct alignas(16) Corner16 { unsigned lo, hi; __half2 w01; __half2 w2_; };
__device__ inline Corner16 pack_corner(int i0, int i1, int i2,
                                       float w0, float w1, float w2) {
    unsigned long long x = (unsigned long long)(unsigned)i0
                         | ((unsigned long long)(unsigned)i1 << 21)
                         | ((unsigned long long)(unsigned)i2 << 42);
    Corner16 c;
    c.lo = (unsigned)x;
    c.hi = (unsigned)(x >> 32);
    c.w01 = __floats2half2_rn(w0, w1);
    c.w2_ = __floats2half2_rn(w2, 0.0f);
    return c;
}

// ---------------------------------------------------------------------------
// K1: two roles:
//   [0, TRB):      verts (B,V,3) -> vertsT (8,V) float4 per-batch slices
//                  (fp32! positions must NOT be quantized pre-cross-product).
//                  Each slice is 1.6 MB -> fits one XCD's 4 MB L2.
//   [TRB, TRB+EB): per-block bucket histograms (LDS atomics only).
// ---------------------------------------------------------------------------
__global__ void k1_pre(const float* __restrict__ verts,
                       float4* __restrict__ vertsT,         // (8,V)
                       const int* __restrict__ vi,
                       int* __restrict__ hist) {            // (EB, NBUK)
    __shared__ int lh[NBUK];
    int blk = blockIdx.x;
    if (blk < TRB) {
        int v = blk * 256 + threadIdx.x;
        if (v >= V) return;
#pragma unroll
        for (int b = 0; b < 8; ++b) {
            const float* p = verts + (size_t)b * V * 3 + (size_t)v * 3;
            vertsT[(size_t)b * V + v] = make_float4(p[0], p[1], p[2], 0.0f);
        }
    } else {
        int k = blk - TRB;
        for (int i = threadIdx.x; i < NBUK; i += 256) lh[i] = 0;
        __syncthreads();
        int m4 = k * 256 + threadIdx.x;
        if (m4 < N4) {
            int4 e = ((const int4*)vi)[m4];
            atomicAdd(&lh[e.x >> 7], 1);
            atomicAdd(&lh[e.y >> 7], 1);
            atomicAdd(&lh[e.z >> 7], 1);
            atomicAdd(&lh[e.w >> 7], 1);
        }
        __syncthreads();
        for (int b = threadIdx.x; b < NBUK; b += 256) hist[k * NBUK + b] = lh[b];
    }
}

// ---------------------------------------------------------------------------
// K2: three roles, no device atomics:
//   [0, FNB2):           face normals, batch-per-XCD: b = blk&7, one face per
//                        thread. Gathers = 3 aligned float4 loads from the
//                        XCD-resident 1.6 MB vertsT slice (1 L2 req each).
//                        Writes fnT (8,F) batch-major, coalesced.
//   [FNB2, +CPB):        corner precompute, TQ=2 samples per thread
//   [FNB2+CPB, +NBUK):   per-bucket exclusive scan over EB block counts
// ---------------------------------------------------------------------------
__global__ void k2_fused(const int* __restrict__ vi,          // (F,3) flat
                         const float4* __restrict__ vertsT,   // (8,V)
                         h4* __restrict__ fnT,                // (8,F)
                         const int* __restrict__ index_image, // (U,U,3)
                         const float* __restrict__ bary_image,// (U,U,3)
                         const float* __restrict__ vt,        // (T,2)
                         Corner16* __restrict__ corners,      // (T,4)
                         int* __restrict__ hist,              // (EB,NBUK) -> off
                         int* __restrict__ tot) {             // (NBUK)
    int blk = blockIdx.x;

    if (blk < FNB2) {
        int b = blk & 7;                     // == XCD under round-robin
        int f = (blk >> 3) * 256 + threadIdx.x;
        if (f >= F) return;

        const float4* vb = vertsT + (size_t)b * V;
        int i0 = vi[f * 3 + 0];
        int i1 = vi[f * 3 + 1];
        int i2 = vi[f * 3 + 2];
        float4 p0 = vb[i0];
        float4 p1 = vb[i1];
        float4 p2 = vb[i2];

        float e1x = p1.x - p0.x, e1y = p1.y - p0.y, e1z = p1.z - p0.z;
        float e2x = p2.x - p0.x, e2y = p2.y - p0.y, e2z = p2.z - p0.z;

        float nx = e1y * e2z - e1z * e2y;
        float ny = e1z * e2x - e1x * e2z;
        float nz = e1x * e2y - e1y * e2x;

        float norm = sqrtf(nx * nx + ny * ny + nz * nz);
        float inv = (norm < EPS) ? 1.0f : (1.0f / norm);
        fnT[(size_t)b * F + f] = pack_h4(nx * inv, ny * inv, nz * inv);
        return;
    }

    if (blk < FNB2 + CPB) {
        int tbase = (blk - FNB2) * 256 + threadIdx.x;
        if (tbase >= T / TQ) return;
#pragma unroll
        for (int qq = 0; qq < TQ; ++qq) {
            int t = tbase + qq * (T / TQ);

            float gx = vt[t * 2 + 0];
            float gy = vt[t * 2 + 1];
            float ix = gx * (float)U - 0.5f;
            float iy = gy * (float)U - 0.5f;

            float x0f = floorf(ix);
            float y0f = floorf(iy);
            int x0 = (int)x0f;
            int y0 = (int)y0f;
            float wx1 = ix - x0f, wx0 = 1.0f - wx1;
            float wy1 = iy - y0f, wy0 = 1.0f - wy1;

#pragma unroll
            for (int c = 0; c < 4; ++c) {
                int cy = c >> 1, cx = c & 1;
                int y = y0 + cy;
                int x = x0 + cx;
                int i0 = 0, i1 = 0, i2 = 0;
                float w0 = 0.0f, w1 = 0.0f, w2 = 0.0f;
                if (x >= 0 && x < U && y >= 0 && y < U) {
                    float w = (cy ? wy1 : wy0) * (cx ? wx1 : wx0);
                    int pix = y * U + x;
                    int j0 = index_image[pix * 3 + 0];
                    int j1 = index_image[pix * 3 + 1];
                    int j2 = index_image[pix * 3 + 2];
                    float m = (j0 != -1 && j1 != -1 && j2 != -1) ? 1.0f : 0.0f;
                    float wm = w * m;
                    i0 = min(max(j0, 0), V - 1);
                    i1 = min(max(j1, 0), V - 1);
                    i2 = min(max(j2, 0), V - 1);
                    w0 = wm * bary_image[pix * 3 + 0];
                    w1 = wm * bary_image[pix * 3 + 1];
                    w2 = wm * bary_image[pix * 3 + 2];
                }
                corners[t * 4 + c] = pack_corner(i0, i1, i2, w0, w1, w2);
            }
        }
        return;
    }

    // --- per-bucket scan: bucket b, exclusive-prefix hist[k][b] over k ---
    {
        __shared__ int part[256];
        int b = blk - FNB2 - CPB;
        int th = threadIdx.x;
        int k0 = th * 3;  // 256*3 = 768 >= EB(586)
        int c0 = (k0     < EB) ? hist[(k0    ) * NBUK + b] : 0;
        int c1 = (k0 + 1 < EB) ? hist[(k0 + 1) * NBUK + b] : 0;
        int c2 = (k0 + 2 < EB) ? hist[(k0 + 2) * NBUK + b] : 0;
        int local = c0 + c1 + c2;
        part[th] = local;
        __syncthreads();
        for (int off = 1; off < 256; off <<= 1) {
            int x = (th >= off) ? part[th - off] : 0;
            __syncthreads();
            part[th] += x;
            __syncthreads();
        }
        int excl = part[th] - local;
        if (th == 255) tot[b] = part[255];
        if (k0     < EB) hist[(k0    ) * NBUK + b] = excl;
        if (k0 + 1 < EB) hist[(k0 + 1) * NBUK + b] = excl + c0;
        if (k0 + 2 < EB) hist[(k0 + 2) * NBUK + b] = excl + c0 + c1;
    }
}

// Redundant per-block exclusive scan of tot -> pre[0..NBUK] in LDS.
// MUST be called by ALL NT threads of the block (contains barriers).
template <int NT>
__device__ inline void scan_base(const int* __restrict__ tot,
                                 int* pre, int* part) {
    constexpr int CH = (NBUK + NT - 1) / NT;
    int th = threadIdx.x;
    int loc[CH];
    int local = 0;
#pragma unroll
    for (int j = 0; j < CH; ++j) {
        int idx = th * CH + j;
        int c = (idx < NBUK) ? tot[idx] : 0;
        loc[j] = local;           // exclusive within chunk
        local += c;
    }
    part[th] = local;
    __syncthreads();
    for (int off = 1; off < NT; off <<= 1) {
        int x = (th >= off) ? part[th - off] : 0;
        __syncthreads();
        part[th] += x;
        __syncthreads();
    }
    int excl = part[th] - local;
#pragma unroll
    for (int j = 0; j < CH; ++j) {
        int idx = th * CH + j;
        if (idx < NBUK) pre[idx] = excl + loc[j];
    }
    if (th == NT - 1) pre[NBUK] = part[NT - 1];
    __syncthreads();
}

// ---------------------------------------------------------------------------
// K4: scatter edges to bucket regions (LDS atomics for local rank only).
// pairs[] packs (vloc<<18)|face. 256 threads; scan_base by all threads.
// ---------------------------------------------------------------------------
__global__ void k4_scatter(const int* __restrict__ vi,
                           const int* __restrict__ off,   // (EB,NBUK)
                           const int* __restrict__ tot,   // (NBUK)
                           int* __restrict__ pairs) {     // (3F)
    __shared__ int lh[NBUK];
    __shared__ int pre[NBUK + 1];
    __shared__ int part[256];
    scan_base<256>(tot, pre, part);

    int k = blockIdx.x;
    for (int i = threadIdx.x; i < NBUK; i += 256) lh[i] = 0;
    __syncthreads();
    int m4 = k * 256 + threadIdx.x;
    if (m4 >= N4) return;
    int4 e = ((const int4*)vi)[m4];
    int be = m4 * 4;
    int vv[4] = {e.x, e.y, e.z, e.w};
#pragma unroll
    for (int j = 0; j < 4; ++j) {
        int v = vv[j];
        int b = v >> 7;
        int r = atomicAdd(&lh[b], 1);
        int pos = pre[b] + off[k * NBUK + b] + r;
        pairs[pos] = ((v & 127) << 18) | ((be + j) / 3);
    }
}

// ---------------------------------------------------------------------------
// K5: batch-split ELL gather. Block = (bucket, batch); batch = blk&7 keeps
// each block's fnT gathers inside its XCD's 1.6 MB slice (L2-resident).
// 128 threads: build ELL in LDS from the bucket's pairs slice (streamed),
// then thread vl gathers deg fp16 normals (8 B L2 hits), normalizes, and
// writes vnT (8,V) batch-major coalesced. The 8x ELL rebuild costs only
// streamed pairs reads (2.4 MB x8) — cheap vs the random traffic it kills.
// ---------------------------------------------------------------------------
__global__ __launch_bounds__(128) void k5_gather(
        const int* __restrict__ pairs,
        const int* __restrict__ tot,
        const h4* __restrict__ fnT,      // (8,F)
        h4* __restrict__ vnT) {          // (8,V)
    __shared__ int cnt[128];
    __shared__ int rows[128 * CAP];      // 12.3 KB
    __shared__ int pre[NBUK + 1];
    __shared__ int part[128];
    scan_base<128>(tot, pre, part);      // all 128 threads, uniform barriers

    int tid = threadIdx.x;
    cnt[tid] = 0;
    __syncthreads();

    int bucket = blockIdx.x >> 3;
    int b8     = blockIdx.x & 7;         // == XCD under round-robin
    int start = pre[bucket], end = pre[bucket + 1];
    for (int i = start + tid; i < end; i += 128) {
        int pk = pairs[i];
        int vl = pk >> 18;
        int f = pk & 0x3FFFF;
        int pos = atomicAdd(&cnt[vl], 1);
        if (pos < CAP) rows[vl * CAP + pos] = f;
    }
    __syncthreads();

    int v = (bucket << 7) + tid;
    if (v >= V) return;
    int deg = min(cnt[tid], CAP);
    const h4* fb = fnT + (size_t)b8 * F;

    float ax = 0.0f, ay = 0.0f, az = 0.0f;
    int j = 0;
    for (; j + 1 < deg; j += 2) {
        h4 r0 = fb[rows[tid * CAP + j]];
        h4 r1 = fb[rows[tid * CAP + j + 1]];
        float3 n0 = unpack_h4(r0);
        float3 n1 = unpack_h4(r1);
        ax += n0.x + n1.x; ay += n0.y + n1.y; az += n0.z + n1.z;
    }
    if (j < deg) {
        float3 n = unpack_h4(fb[rows[tid * CAP + j]]);
        ax += n.x; ay += n.y; az += n.z;
    }
    float nn = sqrtf(ax * ax + ay * ay + az * az);
    float inv = (nn < EPS) ? 1.0f : (1.0f / nn);
    vnT[(size_t)b8 * V + v] = pack_h4(ax * inv, ay * inv, az * inv);
}

// ---------------------------------------------------------------------------
// K6: batch-split sampling. Block = (sample-chunk, batch); each block's 12
// vn gathers hit its XCD's 0.8 MB vnT slice (L2-resident — the old (V,8)
// layout cost ~85 MB of cold random 64 B lines here). Corners are streamed
// once per XCD (7 MB x8, sequential). Writes valsT (8,T) coalesced.
// ---------------------------------------------------------------------------
__global__ void sample_points(const h4* __restrict__ vnT,         // (8,V)
                              const Corner16* __restrict__ corners,// (T,4)
                              h4* __restrict__ valsT) {           // (8,T)
    int b = blockIdx.x & 7;
    int t = (blockIdx.x >> 3) * 256 + threadIdx.x;
    if (t >= T) return;
    const h4* vb = vnT + (size_t)b * V;

    float ax = 0.0f, ay = 0.0f, az = 0.0f;
    Corner16 cr[4];
#pragma unroll
    for (int c = 0; c < 4; ++c) cr[c] = corners[t * 4 + c];
    h4 q[12];
#pragma unroll
    for (int c = 0; c < 4; ++c) {
        unsigned long long x = (unsigned long long)cr[c].lo
                             | ((unsigned long long)cr[c].hi << 32);
        int i0 = (int)(x & 0x1FFFFF);
        int i1 = (int)((x >> 21) & 0x1FFFFF);
        int i2 = (int)(x >> 42);
        q[c * 3 + 0] = vb[i0];
        q[c * 3 + 1] = vb[i1];
        q[c * 3 + 2] = vb[i2];
    }
#pragma unroll
    for (int c = 0; c < 4; ++c) {
        float2 w01 = __half22float2(cr[c].w01);
        float w2 = __low2float(cr[c].w2_);
        float3 q0 = unpack_h4(q[c * 3 + 0]);
        float3 q1 = unpack_h4(q[c * 3 + 1]);
        float3 q2 = unpack_h4(q[c * 3 + 2]);
        ax += w01.x * q0.x + w01.y * q1.x + w2 * q2.x;
        ay += w01.x * q0.y + w01.y * q1.y + w2 * q2.y;
        az += w01.x * q0.z + w01.y * q1.z + w2 * q2.z;
    }
    valsT[(size_t)b * T + t] = pack_h4(ax, ay, az);
}

// ---------------------------------------------------------------------------
// K7: batch-split output gather. Block = (vertex-chunk, batch); the two
// valsT gathers hit the XCD's 0.88 MB slice (L2-resident); out[b] region
// is contiguous per block -> coalesced fp32 writes.
// ---------------------------------------------------------------------------
__global__ void gather_out(const h4* __restrict__ valsT,    // (8,T)
                           const int* __restrict__ v2uv,    // (V,2)
                           float* __restrict__ out) {       // (B,V,3)
    int b = blockIdx.x & 7;
    int v = (blockIdx.x >> 3) * 256 + threadIdx.x;
    if (v >= V) return;

    int t0 = v2uv[v * 2 + 0];
    int t1 = v2uv[v * 2 + 1];
    const h4* vb = valsT + (size_t)b * T;
    float3 x = unpack_h4(vb[t0]);
    float3 y = unpack_h4(vb[t1]);
    float* o = out + (size_t)b * V * 3 + (size_t)v * 3;
    o[0] = 0.5f * (x.x + y.x);
    o[1] = 0.5f * (x.y + y.y);
    o[2] = 0.5f * (x.z + y.z);
}

extern "C" void kernel_launch(void* const* d_in, const int* in_sizes, int n_in,
                              void* d_out, int out_size, void* d_ws, size_t ws_size,
                              hipStream_t stream) {
    const float* verts   = (const float*)d_in[0]; // (B,V,3)
    const float* bary    = (const float*)d_in[1]; // (U,U,3)
    const float* vt      = (const float*)d_in[2]; // (T,2)
    const int*   vi      = (const int*)d_in[3];   // (F,3)
    const int*   idx_img = (const int*)d_in[4];   // (U,U,3)
    const int*   v2uv    = (const int*)d_in[5];   // (V,2)
    float* out = (float*)d_out;

    // Workspace (~37 MB), aliased by stream-ordered disjoint lifetimes:
    //   region A (12.8 MB): vertsT (8,V) f4 (K1 w, K2 r) -> vnT (8,V) h4 6.4 MB (K5 w, K6 r)
    //   region B (12.8 MB): fnT (8,F) h4 (K2 w, K5 r) -> valsT (8,T) h4 7.04 MB (K6 w, K7 r)
    //   region C (7.04 MB): corners 16 B packed (K2 w, K6 r)
    //   region D: hist 1.83 MB, tot 3 KB, pairs 2.4 MB
    float4*   vertsT  = (float4*)d_ws;              // 8*V float4
    h4*       vnT     = (h4*)d_ws;                  // alias (8*V h4)
    h4*       fnT     = (h4*)((char*)d_ws + (size_t)V * 8 * sizeof(float4));
    h4*       valsT   = fnT;                        // alias (8*T h4)
    Corner16* corners = (Corner16*)((char*)fnT + (size_t)F * 8 * sizeof(h4));
    int*      hist    = (int*)(corners + (size_t)T * 4);  // (EB,NBUK)
    int*      tot     = hist + (size_t)EB * NBUK;   // NBUK
    int*      pairs   = tot + NBUK;                 // 3F

    const int BLK = 256;
    k1_pre<<<TRB + EB, BLK, 0, stream>>>(verts, vertsT, vi, hist);
    k2_fused<<<FNB2 + CPB + NBUK, BLK, 0, stream>>>(
        vi, vertsT, fnT, idx_img, bary, vt, corners, hist, tot);
    k4_scatter<<<EB, BLK, 0, stream>>>(vi, hist, tot, pairs);
    k5_gather<<<NBUK * 8, 128, 0, stream>>>(pairs, tot, fnT, vnT);
    sample_points<<<TCH * 8, BLK, 0, stream>>>(vnT, corners, valsT);
    gather_out<<<VCH * 8, BLK, 0, stream>>>(valsT, v2uv, out);
}

// Round 8
// 194.366 us; speedup vs baseline: 1.2352x; 1.2352x over previous
//
#include <hip/hip_runtime.h>
#include <hip/hip_fp16.h>

#define EPS 1e-5f

constexpr int B = 8;
constexpr int V = 100000;
constexpr int F = 200000;
constexpr int U = 1024;
constexpr int T = 110000;
constexpr int CAP = 24;                     // max faces/vertex (data max ~20)

constexpr int NBUK = (V + 127) / 128;       // 782 buckets, 128 vertices each
constexpr int N4   = (3 * F) / 4;           // 150000 int4 edge-quads
constexpr int EB   = (N4 + 255) / 256;      // 586 edge blocks
constexpr int TRB  = (V + 255) / 256;       // 391 transpose blocks

constexpr int FQ   = 8;                     // faces per thread (FN role ILP)
constexpr int FNB  = (F * 8 / FQ + 255) / 256;   // 782 blocks
constexpr int TQ   = 4;                     // samples per thread (corner role)
constexpr int CPB  = (T / TQ + 255) / 256;       // 108 blocks
constexpr int SQ   = 2;                     // samples per thread (k6)
constexpr int VQ   = 2;                     // vertices per thread (k7)

// --- non-temporal helpers -------------------------------------------------
// R7 post-mortem: all gather kernels plateau at ~2.5 TB/s (random 64B-line
// regime); the lever left is BYTES. k2/k5/k6 each mix a reused gather target
// (vertsT 6x, fn 3x, vn 13x reuse) with pure streams (idx/bary/corners/pairs)
// and write-once outputs that pollute L2 and evict the reused lines. Mark
// every read-once load and write-once store non-temporal; leave the reused
// gather targets on the normal cache path.
typedef int i32x4 __attribute__((ext_vector_type(4)));
typedef unsigned long long u64;
__device__ inline float ntl_f(const float* p) { return __builtin_nontemporal_load(p); }
__device__ inline int   ntl_i(const int* p)   { return __builtin_nontemporal_load(p); }
__device__ inline int4  ntl_i4(const int* p) {
    i32x4 v = __builtin_nontemporal_load((const i32x4*)p);
    return make_int4(v.x, v.y, v.z, v.w);
}

// packed half4 (8 B): x,y,z in halves, w pad
struct alignas(8) h4 { __half2 a, b; };
__device__ inline h4 pack_h4(float x, float y, float z) {
    h4 r; r.a = __floats2half2_rn(x, y); r.b = __floats2half2_rn(z, 0.0f);
    return r;
}
__device__ inline float3 unpack_h4(h4 v) {
    float2 xy = __half22float2(v.a);
    float2 zw = __half22float2(v.b);
    return make_float3(xy.x, xy.y, zw.x);
}
__device__ inline void nts_h4(h4* p, h4 v) {
    __builtin_nontemporal_store(__builtin_bit_cast(u64, v), (u64*)p);
}

// 16 B corner record: 3x21-bit indices packed in (lo,hi) + half weights
struct alignas(16) Corner16 { unsigned lo, hi; __half2 w01; __half2 w2_; };
__device__ inline Corner16 pack_corner(int i0, int i1, int i2,
                                       float w0, float w1, float w2) {
    unsigned long long x = (unsigned long long)(unsigned)i0
                         | ((unsigned long long)(unsigned)i1 << 21)
                         | ((unsigned long long)(unsigned)i2 << 42);
    Corner16 c;
    c.lo = (unsigned)x;
    c.hi = (unsigned)(x >> 32);
    c.w01 = __floats2half2_rn(w0, w1);
    c.w2_ = __floats2half2_rn(w2, 0.0f);
    return c;
}
__device__ inline void nts_c16(Corner16* p, Corner16 c) {
    __builtin_nontemporal_store(__builtin_bit_cast(i32x4, c), (i32x4*)p);
}
__device__ inline Corner16 ntl_c16(const Corner16* p) {
    return __builtin_bit_cast(Corner16,
        __builtin_nontemporal_load((const i32x4*)p));
}

// ---------------------------------------------------------------------------
// K1: transpose verts -> (V,8) float4 rows (fp32! — positions must NOT be
// quantized before the cross product) || per-block bucket histograms.
// verts/vi loads are read-once -> non-temporal.
// ---------------------------------------------------------------------------
__global__ void k1_pre(const float* __restrict__ verts,
                       float4* __restrict__ vertsT,
                       const int* __restrict__ vi,
                       int* __restrict__ hist) {    // (EB, NBUK)
    __shared__ int lh[NBUK];
    int blk = blockIdx.x;
    if (blk < TRB) {
        int v = blk * 256 + threadIdx.x;
        if (v >= V) return;
        float4 row[8];
#pragma unroll
        for (int b = 0; b < 8; ++b) {
            const float* p = verts + (size_t)b * V * 3 + (size_t)v * 3;
            row[b] = make_float4(ntl_f(p), ntl_f(p + 1), ntl_f(p + 2), 0.0f);
        }
        float4* dst = vertsT + (size_t)v * 8;
#pragma unroll
        for (int b = 0; b < 8; ++b) dst[b] = row[b];
    } else {
        int k = blk - TRB;
        for (int i = threadIdx.x; i < NBUK; i += 256) lh[i] = 0;
        __syncthreads();
        int m4 = k * 256 + threadIdx.x;
        if (m4 < N4) {
            int4 e = ntl_i4(vi + (size_t)m4 * 4);
            atomicAdd(&lh[e.x >> 7], 1);
            atomicAdd(&lh[e.y >> 7], 1);
            atomicAdd(&lh[e.z >> 7], 1);
            atomicAdd(&lh[e.w >> 7], 1);
        }
        __syncthreads();
        for (int b = threadIdx.x; b < NBUK; b += 256) hist[k * NBUK + b] = lh[b];
    }
}

// ---------------------------------------------------------------------------
// K2: three roles, no device atomics:
//   [0, FNB):            face normals, FQ=8 faces/thread. vertsT gathers are
//                        the protected hot set (6x reuse/row); vi loads and
//                        fn stores are non-temporal so they don't evict it.
//   [FNB, FNB+CPB):      corner precompute. idx/bary/vt loads + corner
//                        stores all non-temporal (pure streams, and this
//                        role runs CONCURRENTLY with FN on the same L2s).
//   [FNB+CPB, +NBUK):    per-bucket exclusive scan over EB block counts.
// ---------------------------------------------------------------------------
__global__ __launch_bounds__(256, 3) void k2_fused(
                         const int* __restrict__ vi,          // (F,3) flat
                         const float4* __restrict__ vertsT,   // (V,8)
                         h4* __restrict__ fn,                 // (F,8)
                         const int* __restrict__ index_image, // (U,U,3)
                         const float* __restrict__ bary_image,// (U,U,3)
                         const float* __restrict__ vt,        // (T,2)
                         Corner16* __restrict__ corners,      // (T,4)
                         int* __restrict__ hist,              // (EB,NBUK) -> off
                         int* __restrict__ tot) {             // (NBUK)
    int blk = blockIdx.x;

    if (blk < FNB) {
        int id = blk * 256 + threadIdx.x;
        if (id >= F * 8 / FQ) return;
        int b = id & 7;
        int fbase = id >> 3;                 // [0, F/FQ)

        // issue all 3*FQ position gathers (FQ independent face streams)
        int ia[FQ], ib[FQ], ic[FQ];
        float4 p0[FQ], p1[FQ], p2[FQ];
#pragma unroll
        for (int q = 0; q < FQ; ++q) {
            int f = fbase + q * (F / FQ);
            ia[q] = ntl_i(vi + f * 3 + 0);
            ib[q] = ntl_i(vi + f * 3 + 1);
            ic[q] = ntl_i(vi + f * 3 + 2);
        }
#pragma unroll
        for (int q = 0; q < FQ; ++q) {
            p0[q] = vertsT[(size_t)ia[q] * 8 + b];
            p1[q] = vertsT[(size_t)ib[q] * 8 + b];
            p2[q] = vertsT[(size_t)ic[q] * 8 + b];
        }
#pragma unroll
        for (int q = 0; q < FQ; ++q) {
            int f = fbase + q * (F / FQ);
            float e1x = p1[q].x - p0[q].x, e1y = p1[q].y - p0[q].y, e1z = p1[q].z - p0[q].z;
            float e2x = p2[q].x - p0[q].x, e2y = p2[q].y - p0[q].y, e2z = p2[q].z - p0[q].z;

            float nx = e1y * e2z - e1z * e2y;
            float ny = e1z * e2x - e1x * e2z;
            float nz = e1x * e2y - e1y * e2x;

            float norm = sqrtf(nx * nx + ny * ny + nz * nz);
            float inv = (norm < EPS) ? 1.0f : (1.0f / norm);
            nts_h4(&fn[(size_t)f * 8 + b], pack_h4(nx * inv, ny * inv, nz * inv));
        }
        return;
    }

    if (blk < FNB + CPB) {
        int tbase = (blk - FNB) * 256 + threadIdx.x;
        if (tbase >= T / TQ) return;
#pragma unroll
        for (int qq = 0; qq < TQ; ++qq) {
            int t = tbase + qq * (T / TQ);

            float gx = ntl_f(vt + t * 2 + 0);
            float gy = ntl_f(vt + t * 2 + 1);
            float ix = gx * (float)U - 0.5f;
            float iy = gy * (float)U - 0.5f;

            float x0f = floorf(ix);
            float y0f = floorf(iy);
            int x0 = (int)x0f;
            int y0 = (int)y0f;
            float wx1 = ix - x0f, wx0 = 1.0f - wx1;
            float wy1 = iy - y0f, wy0 = 1.0f - wy1;

#pragma unroll
            for (int c = 0; c < 4; ++c) {
                int cy = c >> 1, cx = c & 1;
                int y = y0 + cy;
                int x = x0 + cx;
                int i0 = 0, i1 = 0, i2 = 0;
                float w0 = 0.0f, w1 = 0.0f, w2 = 0.0f;
                if (x >= 0 && x < U && y >= 0 && y < U) {
                    float w = (cy ? wy1 : wy0) * (cx ? wx1 : wx0);
                    int pix = y * U + x;
                    int j0 = ntl_i(index_image + pix * 3 + 0);
                    int j1 = ntl_i(index_image + pix * 3 + 1);
                    int j2 = ntl_i(index_image + pix * 3 + 2);
                    float m = (j0 != -1 && j1 != -1 && j2 != -1) ? 1.0f : 0.0f;
                    float wm = w * m;
                    i0 = min(max(j0, 0), V - 1);
                    i1 = min(max(j1, 0), V - 1);
                    i2 = min(max(j2, 0), V - 1);
                    w0 = wm * ntl_f(bary_image + pix * 3 + 0);
                    w1 = wm * ntl_f(bary_image + pix * 3 + 1);
                    w2 = wm * ntl_f(bary_image + pix * 3 + 2);
                }
                nts_c16(&corners[t * 4 + c], pack_corner(i0, i1, i2, w0, w1, w2));
            }
        }
        return;
    }

    // --- per-bucket scan: bucket b, exclusive-prefix hist[k][b] over k ---
    {
        __shared__ int part[256];
        int b = blk - FNB - CPB;
        int th = threadIdx.x;
        int k0 = th * 3;  // 256*3 = 768 >= EB(586)
        int c0 = (k0     < EB) ? hist[(k0    ) * NBUK + b] : 0;
        int c1 = (k0 + 1 < EB) ? hist[(k0 + 1) * NBUK + b] : 0;
        int c2 = (k0 + 2 < EB) ? hist[(k0 + 2) * NBUK + b] : 0;
        int local = c0 + c1 + c2;
        part[th] = local;
        __syncthreads();
        for (int off = 1; off < 256; off <<= 1) {
            int x = (th >= off) ? part[th - off] : 0;
            __syncthreads();
            part[th] += x;
            __syncthreads();
        }
        int excl = part[th] - local;
        if (th == 255) tot[b] = part[255];
        if (k0     < EB) hist[(k0    ) * NBUK + b] = excl;
        if (k0 + 1 < EB) hist[(k0 + 1) * NBUK + b] = excl + c0;
        if (k0 + 2 < EB) hist[(k0 + 2) * NBUK + b] = excl + c0 + c1;
    }
}

// Redundant per-block exclusive scan of tot -> pre[0..NBUK] in LDS.
// MUST be called by ALL threads of a 256-thread block (contains barriers).
__device__ inline void scan_base(const int* __restrict__ tot,
                                 int* pre, int* part) {
    constexpr int CH = (NBUK + 255) / 256;  // 4
    int th = threadIdx.x;
    int loc[CH];
    int local = 0;
#pragma unroll
    for (int j = 0; j < CH; ++j) {
        int idx = th * CH + j;
        int c = (idx < NBUK) ? tot[idx] : 0;
        loc[j] = local;           // exclusive within chunk
        local += c;
    }
    part[th] = local;
    __syncthreads();
    for (int off = 1; off < 256; off <<= 1) {
        int x = (th >= off) ? part[th - off] : 0;
        __syncthreads();
        part[th] += x;
        __syncthreads();
    }
    int excl = part[th] - local;
#pragma unroll
    for (int j = 0; j < CH; ++j) {
        int idx = th * CH + j;
        if (idx < NBUK) pre[idx] = excl + loc[j];
    }
    if (th == 255) pre[NBUK] = part[255];
    __syncthreads();
}

// ---------------------------------------------------------------------------
// K4: scatter edges to bucket regions (LDS atomics for local rank only).
// pairs[] packs (vloc<<18)|face. vi load is read-once -> non-temporal.
// ---------------------------------------------------------------------------
__global__ void k4_scatter(const int* __restrict__ vi,
                           const int* __restrict__ off,   // (EB,NBUK)
                           const int* __restrict__ tot,   // (NBUK)
                           int* __restrict__ pairs) {     // (3F)
    __shared__ int lh[NBUK];
    __shared__ int pre[NBUK + 1];
    __shared__ int part[256];
    scan_base(tot, pre, part);

    int k = blockIdx.x;
    for (int i = threadIdx.x; i < NBUK; i += 256) lh[i] = 0;
    __syncthreads();
    int m4 = k * 256 + threadIdx.x;
    if (m4 >= N4) return;
    int4 e = ntl_i4(vi + (size_t)m4 * 4);
    int be = m4 * 4;
    int vv[4] = {e.x, e.y, e.z, e.w};
#pragma unroll
    for (int j = 0; j < 4; ++j) {
        int v = vv[j];
        int b = v >> 7;
        int r = atomicAdd(&lh[b], 1);
        int pos = pre[b] + off[k * NBUK + b] + r;
        pairs[pos] = ((v & 127) << 18) | ((be + j) / 3);
    }
}

// ---------------------------------------------------------------------------
// K5: per-bucket ELL build in LDS + fp16 fn gather + normalize -> fp16 vn.
// pairs loads (stream) + vn stores (write-once) non-temporal; fn gathers
// (3x line reuse) stay on the normal cache path.
// ---------------------------------------------------------------------------
__global__ __launch_bounds__(256) void k5_gather(
        const int* __restrict__ pairs,
        const int* __restrict__ tot,
        const h4* __restrict__ fn,       // (F,8)
        h4* __restrict__ vn) {           // (V,8)
    __shared__ int cnt[128];
    __shared__ int rows[128 * CAP];      // 12.3 KB
    __shared__ int pre[NBUK + 1];
    __shared__ int part[256];
    scan_base(tot, pre, part);           // all 256 threads, uniform barriers

    int tid = threadIdx.x;
    if (tid < 128) cnt[tid] = 0;
    __syncthreads();

    int b = blockIdx.x;
    int start = pre[b], end = pre[b + 1];
    for (int i = start + tid; i < end; i += 256) {
        int pk = ntl_i(pairs + i);
        int vl = pk >> 18;
        int f = pk & 0x3FFFF;
        int pos = atomicAdd(&cnt[vl], 1);
        if (pos < CAP) rows[vl * CAP + pos] = f;
    }
    __syncthreads();

    int v0 = b << 7;
    for (int id = tid; id < 128 * 8; id += 256) {
        int vl = id >> 3, b8 = id & 7;
        int v = v0 + vl;
        if (v >= V) continue;
        int deg = min(cnt[vl], CAP);
        float ax = 0.0f, ay = 0.0f, az = 0.0f;
        int j = 0;
        for (; j + 1 < deg; j += 2) {
            h4 r0 = fn[(size_t)rows[vl * CAP + j] * 8 + b8];
            h4 r1 = fn[(size_t)rows[vl * CAP + j + 1] * 8 + b8];
            float3 n0 = unpack_h4(r0);
            float3 n1 = unpack_h4(r1);
            ax += n0.x + n1.x; ay += n0.y + n1.y; az += n0.z + n1.z;
        }
        if (j < deg) {
            float3 n = unpack_h4(fn[(size_t)rows[vl * CAP + j] * 8 + b8]);
            ax += n.x; ay += n.y; az += n.z;
        }
        float nn = sqrtf(ax * ax + ay * ay + az * az);
        float inv = (nn < EPS) ? 1.0f : (1.0f / nn);
        nts_h4(&vn[(size_t)v * 8 + b8], pack_h4(ax * inv, ay * inv, az * inv));
    }
}

// ---------------------------------------------------------------------------
// K6: sample with 16 B packed corners, SQ=2 samples per thread. 8 lanes
// share each t -> corner loads broadcast, vn gathers share full 64 B lines
// (13x line reuse -> protected). corners loads (stream) + vals stores
// (write-once) non-temporal.
// ---------------------------------------------------------------------------
__global__ __launch_bounds__(256, 4) void sample_points(
                              const h4* __restrict__ vn,           // (V,8)
                              const Corner16* __restrict__ corners,// (T,4)
                              h4* __restrict__ vals) {             // (T,8)
    int id = blockIdx.x * blockDim.x + threadIdx.x;
    if (id >= (T / SQ) * 8) return;
    int b = id & 7;
    int tb = id >> 3;

#pragma unroll
    for (int s = 0; s < SQ; ++s) {
        int t = tb + s * (T / SQ);
        float ax = 0.0f, ay = 0.0f, az = 0.0f;
        Corner16 cr[4];
#pragma unroll
        for (int c = 0; c < 4; ++c) cr[c] = ntl_c16(&corners[t * 4 + c]);
        h4 q[12];
#pragma unroll
        for (int c = 0; c < 4; ++c) {
            unsigned long long x = (unsigned long long)cr[c].lo
                                 | ((unsigned long long)cr[c].hi << 32);
            int i0 = (int)(x & 0x1FFFFF);
            int i1 = (int)((x >> 21) & 0x1FFFFF);
            int i2 = (int)(x >> 42);
            q[c * 3 + 0] = vn[(size_t)i0 * 8 + b];
            q[c * 3 + 1] = vn[(size_t)i1 * 8 + b];
            q[c * 3 + 2] = vn[(size_t)i2 * 8 + b];
        }
#pragma unroll
        for (int c = 0; c < 4; ++c) {
            float2 w01 = __half22float2(cr[c].w01);
            float w2 = __low2float(cr[c].w2_);
            float3 q0 = unpack_h4(q[c * 3 + 0]);
            float3 q1 = unpack_h4(q[c * 3 + 1]);
            float3 q2 = unpack_h4(q[c * 3 + 2]);
            ax += w01.x * q0.x + w01.y * q1.x + w2 * q2.x;
            ay += w01.x * q0.y + w01.y * q1.y + w2 * q2.y;
            az += w01.x * q0.z + w01.y * q1.z + w2 * q2.z;
        }
        nts_h4(&vals[(size_t)t * 8 + b], pack_h4(ax, ay, az));
    }
}

// ---------------------------------------------------------------------------
// K7: out[b,v,:] = mean over K=2 of vals[v2uv[v,k], b]. v2uv loads (stream)
// + out stores (final output) non-temporal; vals gathers protected.
// ---------------------------------------------------------------------------
__global__ void gather_out(const h4* __restrict__ vals,     // (T,8)
                           const int* __restrict__ v2uv,    // (V,2)
                           float* __restrict__ out) {       // (B,V,3)
    int id = blockIdx.x * blockDim.x + threadIdx.x;
    if (id >= (V / VQ) * 8) return;
    int b = id & 7;
    int vb = id >> 3;

    int t0[VQ], t1[VQ];
    h4 xa[VQ], ya[VQ];
#pragma unroll
    for (int s = 0; s < VQ; ++s) {
        int v = vb + s * (V / VQ);
        t0[s] = ntl_i(v2uv + v * 2 + 0);
        t1[s] = ntl_i(v2uv + v * 2 + 1);
    }
#pragma unroll
    for (int s = 0; s < VQ; ++s) {
        xa[s] = vals[(size_t)t0[s] * 8 + b];
        ya[s] = vals[(size_t)t1[s] * 8 + b];
    }
#pragma unroll
    for (int s = 0; s < VQ; ++s) {
        int v = vb + s * (V / VQ);
        float3 x = unpack_h4(xa[s]);
        float3 y = unpack_h4(ya[s]);
        float* o = out + (size_t)b * V * 3 + (size_t)v * 3;
        __builtin_nontemporal_store(0.5f * (x.x + y.x), o + 0);
        __builtin_nontemporal_store(0.5f * (x.y + y.y), o + 1);
        __builtin_nontemporal_store(0.5f * (x.z + y.z), o + 2);
    }
}

extern "C" void kernel_launch(void* const* d_in, const int* in_sizes, int n_in,
                              void* d_out, int out_size, void* d_ws, size_t ws_size,
                              hipStream_t stream) {
    const float* verts   = (const float*)d_in[0]; // (B,V,3)
    const float* bary    = (const float*)d_in[1]; // (U,U,3)
    const float* vt      = (const float*)d_in[2]; // (T,2)
    const int*   vi      = (const int*)d_in[3];   // (F,3)
    const int*   idx_img = (const int*)d_in[4];   // (U,U,3)
    const int*   v2uv    = (const int*)d_in[5];   // (V,2)
    float* out = (float*)d_out;

    // Workspace (~37 MB), aliased by stream-ordered disjoint lifetimes:
    //   region A (12.8 MB): vertsT fp32 (K1 w, K2 r) -> vn h4 6.4 MB (K5 w, K6 r)
    //   region B (12.8 MB): fn h4 (K2 w, K5 r) -> vals h4 7.04 MB (K6 w, K7 r)
    //   region C (7.04 MB): corners 16 B packed (K2 w, K6 r)
    //   region D: hist 1.83 MB, tot 3 KB, pairs 2.4 MB
    float4*   vertsT  = (float4*)d_ws;
    h4*       vn      = (h4*)d_ws;                  // alias
    h4*       fn      = (h4*)(vertsT + (size_t)V * 8);
    h4*       vals    = fn;                         // alias
    Corner16* corners = (Corner16*)((char*)fn + (size_t)F * 8 * sizeof(h4));
    int*      hist    = (int*)(corners + (size_t)T * 4);  // (EB,NBUK)
    int*      tot     = hist + (size_t)EB * NBUK;   // NBUK
    int*      pairs   = tot + NBUK;                 // 3F

    const int BLK = 256;
    k1_pre<<<TRB + EB, BLK, 0, stream>>>(verts, vertsT, vi, hist);
    k2_fused<<<FNB + CPB + NBUK, BLK, 0, stream>>>(
        vi, vertsT, fn, idx_img, bary, vt, corners, hist, tot);
    k4_scatter<<<EB, BLK, 0, stream>>>(vi, hist, tot, pairs);
    k5_gather<<<NBUK, BLK, 0, stream>>>(pairs, tot, fn, vn);
    sample_points<<<((T / SQ) * 8 + BLK - 1) / BLK, BLK, 0, stream>>>(
        vn, corners, vals);
    gather_out<<<((V / VQ) * 8 + BLK - 1) / BLK, BLK, 0, stream>>>(
        vals, v2uv, out);
}

// Round 9
// 172.829 us; speedup vs baseline: 1.3891x; 1.1246x over previous
//
#include <hip/hip_runtime.h>
#include <hip/hip_fp16.h>

#define EPS 1e-5f

constexpr int B = 8;
constexpr int V = 100000;
constexpr int F = 200000;
constexpr int U = 1024;
constexpr int T = 110000;
constexpr int CAP = 24;                     // max faces/vertex (data max ~20)

constexpr int NBUK = (V + 127) / 128;       // 782 buckets, 128 vertices each
constexpr int N4   = (3 * F) / 4;           // 150000 int4 edge-quads
constexpr int EB   = (N4 + 255) / 256;      // 586 edge blocks
constexpr int TRB  = (V + 255) / 256;       // 391 transpose blocks

constexpr int FQ   = 8;                     // faces per thread (FN role ILP)
constexpr int FNB  = (F * 8 / FQ + 255) / 256;   // 782 blocks
constexpr int TQ   = 4;                     // samples per thread (corner role)
constexpr int CPB  = (T / TQ + 255) / 256;       // 108 blocks
constexpr int SQ   = 2;                     // samples per thread (k6)
constexpr int VQ   = 2;                     // vertices per thread (k7)

// Session ledger (why this exact shape):
//  R1-R3: scan-kill / atomic-cursor / global-ELL restructures — all slower
//         (global 4 B scatter amplifies ~2x at HBM; scan machinery is cheap).
//  R4: launch_bounds register-budget hints — neutral (allocator ignores cap).
//  R5: FQ=2 TLP — slower; throughput pinned at ~2.5 TB/s regardless of waves.
//  R6/R7: batch-per-XCD layouts — FETCH dropped but BW dropped more (16 B of
//         every 64 B line used); batch-row line sharing is load-bearing.
//  R8: non-temporal hints — FETCH +18 MB (nt defeats the short-range L2 reuse
//      of idx/bary/corner-neighbor lines), WRITE +6 MB, −20 us.
//  => This R0/R4 structure (174.2 us, verified twice) is the converged form:
//     random-gather fabric throughput ~2.5 TB/s is the binding constraint.

// packed half4 (8 B): x,y,z in halves, w pad
struct alignas(8) h4 { __half2 a, b; };
__device__ inline h4 pack_h4(float x, float y, float z) {
    h4 r; r.a = __floats2half2_rn(x, y); r.b = __floats2half2_rn(z, 0.0f);
    return r;
}
__device__ inline float3 unpack_h4(h4 v) {
    float2 xy = __half22float2(v.a);
    float2 zw = __half22float2(v.b);
    return make_float3(xy.x, xy.y, zw.x);
}

// 16 B corner record: 3x21-bit indices packed in (lo,hi) + half weights
struct alignas(16) Corner16 { unsigned lo, hi; __half2 w01; __half2 w2_; };
__device__ inline Corner16 pack_corner(int i0, int i1, int i2,
                                       float w0, float w1, float w2) {
    unsigned long long x = (unsigned long long)(unsigned)i0
                         | ((unsigned long long)(unsigned)i1 << 21)
                         | ((unsigned long long)(unsigned)i2 << 42);
    Corner16 c;
    c.lo = (unsigned)x;
    c.hi = (unsigned)(x >> 32);
    c.w01 = __floats2half2_rn(w0, w1);
    c.w2_ = __floats2half2_rn(w2, 0.0f);
    return c;
}

// ---------------------------------------------------------------------------
// K1: transpose verts -> (V,8) float4 rows (fp32! — positions must NOT be
// quantized before the cross product; fp16 here failed absmax 0.034>0.030)
// || per-block bucket histograms (LDS atomics only).
// ---------------------------------------------------------------------------
__global__ void k1_pre(const float* __restrict__ verts,
                       float4* __restrict__ vertsT,
                       const int* __restrict__ vi,
                       int* __restrict__ hist) {    // (EB, NBUK)
    __shared__ int lh[NBUK];
    int blk = blockIdx.x;
    if (blk < TRB) {
        int v = blk * 256 + threadIdx.x;
        if (v >= V) return;
        float4 row[8];
#pragma unroll
        for (int b = 0; b < 8; ++b) {
            const float* p = verts + (size_t)b * V * 3 + (size_t)v * 3;
            row[b] = make_float4(p[0], p[1], p[2], 0.0f);
        }
        float4* dst = vertsT + (size_t)v * 8;
#pragma unroll
        for (int b = 0; b < 8; ++b) dst[b] = row[b];
    } else {
        int k = blk - TRB;
        for (int i = threadIdx.x; i < NBUK; i += 256) lh[i] = 0;
        __syncthreads();
        int m4 = k * 256 + threadIdx.x;
        if (m4 < N4) {
            int4 e = ((const int4*)vi)[m4];
            atomicAdd(&lh[e.x >> 7], 1);
            atomicAdd(&lh[e.y >> 7], 1);
            atomicAdd(&lh[e.z >> 7], 1);
            atomicAdd(&lh[e.w >> 7], 1);
        }
        __syncthreads();
        for (int b = threadIdx.x; b < NBUK; b += 256) hist[k * NBUK + b] = lh[b];
    }
}

// ---------------------------------------------------------------------------
// K2: three roles, no device atomics:
//   [0, FNB):            face normals, FQ=8 faces per thread (24 gathers
//                        in flight per lane), fp16 out
//   [FNB, FNB+CPB):      corner precompute, TQ=4 samples per thread
//   [FNB+CPB, +NBUK):    per-bucket exclusive scan over EB block counts
// ---------------------------------------------------------------------------
__global__ __launch_bounds__(256, 3) void k2_fused(
                         const int* __restrict__ vi,          // (F,3) flat
                         const float4* __restrict__ vertsT,   // (V,8)
                         h4* __restrict__ fn,                 // (F,8)
                         const int* __restrict__ index_image, // (U,U,3)
                         const float* __restrict__ bary_image,// (U,U,3)
                         const float* __restrict__ vt,        // (T,2)
                         Corner16* __restrict__ corners,      // (T,4)
                         int* __restrict__ hist,              // (EB,NBUK) -> off
                         int* __restrict__ tot) {             // (NBUK)
    int blk = blockIdx.x;

    if (blk < FNB) {
        int id = blk * 256 + threadIdx.x;
        if (id >= F * 8 / FQ) return;
        int b = id & 7;
        int fbase = id >> 3;                 // [0, F/FQ)

        // issue all 3*FQ position gathers (FQ independent face streams)
        int ia[FQ], ib[FQ], ic[FQ];
        float4 p0[FQ], p1[FQ], p2[FQ];
#pragma unroll
        for (int q = 0; q < FQ; ++q) {
            int f = fbase + q * (F / FQ);
            ia[q] = vi[f * 3 + 0];
            ib[q] = vi[f * 3 + 1];
            ic[q] = vi[f * 3 + 2];
        }
#pragma unroll
        for (int q = 0; q < FQ; ++q) {
            p0[q] = vertsT[(size_t)ia[q] * 8 + b];
            p1[q] = vertsT[(size_t)ib[q] * 8 + b];
            p2[q] = vertsT[(size_t)ic[q] * 8 + b];
        }
#pragma unroll
        for (int q = 0; q < FQ; ++q) {
            int f = fbase + q * (F / FQ);
            float e1x = p1[q].x - p0[q].x, e1y = p1[q].y - p0[q].y, e1z = p1[q].z - p0[q].z;
            float e2x = p2[q].x - p0[q].x, e2y = p2[q].y - p0[q].y, e2z = p2[q].z - p0[q].z;

            float nx = e1y * e2z - e1z * e2y;
            float ny = e1z * e2x - e1x * e2z;
            float nz = e1x * e2y - e1y * e2x;

            float norm = sqrtf(nx * nx + ny * ny + nz * nz);
            float inv = (norm < EPS) ? 1.0f : (1.0f / norm);
            fn[(size_t)f * 8 + b] = pack_h4(nx * inv, ny * inv, nz * inv);
        }
        return;
    }

    if (blk < FNB + CPB) {
        int tbase = (blk - FNB) * 256 + threadIdx.x;
        if (tbase >= T / TQ) return;
#pragma unroll
        for (int qq = 0; qq < TQ; ++qq) {
            int t = tbase + qq * (T / TQ);

            float gx = vt[t * 2 + 0];
            float gy = vt[t * 2 + 1];
            float ix = gx * (float)U - 0.5f;
            float iy = gy * (float)U - 0.5f;

            float x0f = floorf(ix);
            float y0f = floorf(iy);
            int x0 = (int)x0f;
            int y0 = (int)y0f;
            float wx1 = ix - x0f, wx0 = 1.0f - wx1;
            float wy1 = iy - y0f, wy0 = 1.0f - wy1;

#pragma unroll
            for (int c = 0; c < 4; ++c) {
                int cy = c >> 1, cx = c & 1;
                int y = y0 + cy;
                int x = x0 + cx;
                int i0 = 0, i1 = 0, i2 = 0;
                float w0 = 0.0f, w1 = 0.0f, w2 = 0.0f;
                if (x >= 0 && x < U && y >= 0 && y < U) {
                    float w = (cy ? wy1 : wy0) * (cx ? wx1 : wx0);
                    int pix = y * U + x;
                    int j0 = index_image[pix * 3 + 0];
                    int j1 = index_image[pix * 3 + 1];
                    int j2 = index_image[pix * 3 + 2];
                    float m = (j0 != -1 && j1 != -1 && j2 != -1) ? 1.0f : 0.0f;
                    float wm = w * m;
                    i0 = min(max(j0, 0), V - 1);
                    i1 = min(max(j1, 0), V - 1);
                    i2 = min(max(j2, 0), V - 1);
                    w0 = wm * bary_image[pix * 3 + 0];
                    w1 = wm * bary_image[pix * 3 + 1];
                    w2 = wm * bary_image[pix * 3 + 2];
                }
                corners[t * 4 + c] = pack_corner(i0, i1, i2, w0, w1, w2);
            }
        }
        return;
    }

    // --- per-bucket scan: bucket b, exclusive-prefix hist[k][b] over k ---
    {
        __shared__ int part[256];
        int b = blk - FNB - CPB;
        int th = threadIdx.x;
        int k0 = th * 3;  // 256*3 = 768 >= EB(586)
        int c0 = (k0     < EB) ? hist[(k0    ) * NBUK + b] : 0;
        int c1 = (k0 + 1 < EB) ? hist[(k0 + 1) * NBUK + b] : 0;
        int c2 = (k0 + 2 < EB) ? hist[(k0 + 2) * NBUK + b] : 0;
        int local = c0 + c1 + c2;
        part[th] = local;
        __syncthreads();
        for (int off = 1; off < 256; off <<= 1) {
            int x = (th >= off) ? part[th - off] : 0;
            __syncthreads();
            part[th] += x;
            __syncthreads();
        }
        int excl = part[th] - local;
        if (th == 255) tot[b] = part[255];
        if (k0     < EB) hist[(k0    ) * NBUK + b] = excl;
        if (k0 + 1 < EB) hist[(k0 + 1) * NBUK + b] = excl + c0;
        if (k0 + 2 < EB) hist[(k0 + 2) * NBUK + b] = excl + c0 + c1;
    }
}

// Redundant per-block exclusive scan of tot -> pre[0..NBUK] in LDS.
// MUST be called by ALL threads of a 256-thread block (contains barriers).
__device__ inline void scan_base(const int* __restrict__ tot,
                                 int* pre, int* part) {
    constexpr int CH = (NBUK + 255) / 256;  // 4
    int th = threadIdx.x;
    int loc[CH];
    int local = 0;
#pragma unroll
    for (int j = 0; j < CH; ++j) {
        int idx = th * CH + j;
        int c = (idx < NBUK) ? tot[idx] : 0;
        loc[j] = local;           // exclusive within chunk
        local += c;
    }
    part[th] = local;
    __syncthreads();
    for (int off = 1; off < 256; off <<= 1) {
        int x = (th >= off) ? part[th - off] : 0;
        __syncthreads();
        part[th] += x;
        __syncthreads();
    }
    int excl = part[th] - local;
#pragma unroll
    for (int j = 0; j < CH; ++j) {
        int idx = th * CH + j;
        if (idx < NBUK) pre[idx] = excl + loc[j];
    }
    if (th == 255) pre[NBUK] = part[255];
    __syncthreads();
}

// ---------------------------------------------------------------------------
// K4: scatter edges to bucket regions (LDS atomics for local rank only).
// pairs[] packs (vloc<<18)|face. 256 threads; scan_base by all threads.
// ---------------------------------------------------------------------------
__global__ void k4_scatter(const int* __restrict__ vi,
                           const int* __restrict__ off,   // (EB,NBUK)
                           const int* __restrict__ tot,   // (NBUK)
                           int* __restrict__ pairs) {     // (3F)
    __shared__ int lh[NBUK];
    __shared__ int pre[NBUK + 1];
    __shared__ int part[256];
    scan_base(tot, pre, part);

    int k = blockIdx.x;
    for (int i = threadIdx.x; i < NBUK; i += 256) lh[i] = 0;
    __syncthreads();
    int m4 = k * 256 + threadIdx.x;
    if (m4 >= N4) return;
    int4 e = ((const int4*)vi)[m4];
    int be = m4 * 4;
    int vv[4] = {e.x, e.y, e.z, e.w};
#pragma unroll
    for (int j = 0; j < 4; ++j) {
        int v = vv[j];
        int b = v >> 7;
        int r = atomicAdd(&lh[b], 1);
        int pos = pre[b] + off[k * NBUK + b] + r;
        pairs[pos] = ((v & 127) << 18) | ((be + j) / 3);
    }
}

// ---------------------------------------------------------------------------
// K5: per-bucket ELL build in LDS + fp16 fn gather + normalize -> fp16 vn.
// 256 threads (scan_base barrier-uniform). Gather loop unrolled x2 so two
// 64 B fn gathers are always in flight.
// ---------------------------------------------------------------------------
__global__ __launch_bounds__(256) void k5_gather(
        const int* __restrict__ pairs,
        const int* __restrict__ tot,
        const h4* __restrict__ fn,       // (F,8)
        h4* __restrict__ vn) {           // (V,8)
    __shared__ int cnt[128];
    __shared__ int rows[128 * CAP];      // 12.3 KB
    __shared__ int pre[NBUK + 1];
    __shared__ int part[256];
    scan_base(tot, pre, part);           // all 256 threads, uniform barriers

    int tid = threadIdx.x;
    if (tid < 128) cnt[tid] = 0;
    __syncthreads();

    int b = blockIdx.x;
    int start = pre[b], end = pre[b + 1];
    for (int i = start + tid; i < end; i += 256) {
        int pk = pairs[i];
        int vl = pk >> 18;
        int f = pk & 0x3FFFF;
        int pos = atomicAdd(&cnt[vl], 1);
        if (pos < CAP) rows[vl * CAP + pos] = f;
    }
    __syncthreads();

    int v0 = b << 7;
    for (int id = tid; id < 128 * 8; id += 256) {
        int vl = id >> 3, b8 = id & 7;
        int v = v0 + vl;
        if (v >= V) continue;
        int deg = min(cnt[vl], CAP);
        float ax = 0.0f, ay = 0.0f, az = 0.0f;
        int j = 0;
        for (; j + 1 < deg; j += 2) {
            h4 r0 = fn[(size_t)rows[vl * CAP + j] * 8 + b8];
            h4 r1 = fn[(size_t)rows[vl * CAP + j + 1] * 8 + b8];
            float3 n0 = unpack_h4(r0);
            float3 n1 = unpack_h4(r1);
            ax += n0.x + n1.x; ay += n0.y + n1.y; az += n0.z + n1.z;
        }
        if (j < deg) {
            float3 n = unpack_h4(fn[(size_t)rows[vl * CAP + j] * 8 + b8]);
            ax += n.x; ay += n.y; az += n.z;
        }
        float nn = sqrtf(ax * ax + ay * ay + az * az);
        float inv = (nn < EPS) ? 1.0f : (1.0f / nn);
        vn[(size_t)v * 8 + b8] = pack_h4(ax * inv, ay * inv, az * inv);
    }
}

// ---------------------------------------------------------------------------
// K6: sample with 16 B packed corners, SQ=2 samples per thread (24 vn
// gathers in flight). 8 lanes share each t -> corner loads broadcast.
// ---------------------------------------------------------------------------
__global__ __launch_bounds__(256, 4) void sample_points(
                              const h4* __restrict__ vn,           // (V,8)
                              const Corner16* __restrict__ corners,// (T,4)
                              h4* __restrict__ vals) {             // (T,8)
    int id = blockIdx.x * blockDim.x + threadIdx.x;
    if (id >= (T / SQ) * 8) return;
    int b = id & 7;
    int tb = id >> 3;

#pragma unroll
    for (int s = 0; s < SQ; ++s) {
        int t = tb + s * (T / SQ);
        float ax = 0.0f, ay = 0.0f, az = 0.0f;
        Corner16 cr[4];
#pragma unroll
        for (int c = 0; c < 4; ++c) cr[c] = corners[t * 4 + c];
        h4 q[12];
#pragma unroll
        for (int c = 0; c < 4; ++c) {
            unsigned long long x = (unsigned long long)cr[c].lo
                                 | ((unsigned long long)cr[c].hi << 32);
            int i0 = (int)(x & 0x1FFFFF);
            int i1 = (int)((x >> 21) & 0x1FFFFF);
            int i2 = (int)(x >> 42);
            q[c * 3 + 0] = vn[(size_t)i0 * 8 + b];
            q[c * 3 + 1] = vn[(size_t)i1 * 8 + b];
            q[c * 3 + 2] = vn[(size_t)i2 * 8 + b];
        }
#pragma unroll
        for (int c = 0; c < 4; ++c) {
            float2 w01 = __half22float2(cr[c].w01);
            float w2 = __low2float(cr[c].w2_);
            float3 q0 = unpack_h4(q[c * 3 + 0]);
            float3 q1 = unpack_h4(q[c * 3 + 1]);
            float3 q2 = unpack_h4(q[c * 3 + 2]);
            ax += w01.x * q0.x + w01.y * q1.x + w2 * q2.x;
            ay += w01.x * q0.y + w01.y * q1.y + w2 * q2.y;
            az += w01.x * q0.z + w01.y * q1.z + w2 * q2.z;
        }
        vals[(size_t)t * 8 + b] = pack_h4(ax, ay, az);
    }
}

// ---------------------------------------------------------------------------
// K7: out[b,v,:] = mean over K=2 of vals[v2uv[v,k], b]. VQ=2 vertices per
// thread (4 gathers in flight). fp32 output.
// ---------------------------------------------------------------------------
__global__ void gather_out(const h4* __restrict__ vals,     // (T,8)
                           const int* __restrict__ v2uv,    // (V,2)
                           float* __restrict__ out) {       // (B,V,3)
    int id = blockIdx.x * blockDim.x + threadIdx.x;
    if (id >= (V / VQ) * 8) return;
    int b = id & 7;
    int vb = id >> 3;

    int t0[VQ], t1[VQ];
    h4 xa[VQ], ya[VQ];
#pragma unroll
    for (int s = 0; s < VQ; ++s) {
        int v = vb + s * (V / VQ);
        t0[s] = v2uv[v * 2 + 0];
        t1[s] = v2uv[v * 2 + 1];
    }
#pragma unroll
    for (int s = 0; s < VQ; ++s) {
        xa[s] = vals[(size_t)t0[s] * 8 + b];
        ya[s] = vals[(size_t)t1[s] * 8 + b];
    }
#pragma unroll
    for (int s = 0; s < VQ; ++s) {
        int v = vb + s * (V / VQ);
        float3 x = unpack_h4(xa[s]);
        float3 y = unpack_h4(ya[s]);
        float* o = out + (size_t)b * V * 3 + (size_t)v * 3;
        o[0] = 0.5f * (x.x + y.x);
        o[1] = 0.5f * (x.y + y.y);
        o[2] = 0.5f * (x.z + y.z);
    }
}

extern "C" void kernel_launch(void* const* d_in, const int* in_sizes, int n_in,
                              void* d_out, int out_size, void* d_ws, size_t ws_size,
                              hipStream_t stream) {
    const float* verts   = (const float*)d_in[0]; // (B,V,3)
    const float* bary    = (const float*)d_in[1]; // (U,U,3)
    const float* vt      = (const float*)d_in[2]; // (T,2)
    const int*   vi      = (const int*)d_in[3];   // (F,3)
    const int*   idx_img = (const int*)d_in[4];   // (U,U,3)
    const int*   v2uv    = (const int*)d_in[5];   // (V,2)
    float* out = (float*)d_out;

    // Workspace (~37 MB), aliased by stream-ordered disjoint lifetimes:
    //   region A (12.8 MB): vertsT fp32 (K1 w, K2 r) -> vn h4 6.4 MB (K5 w, K6 r)
    //   region B (12.8 MB): fn h4 (K2 w, K5 r) -> vals h4 7.04 MB (K6 w, K7 r)
    //   region C (7.04 MB): corners 16 B packed (K2 w, K6 r)
    //   region D: hist 1.83 MB, tot 3 KB, pairs 2.4 MB
    float4*   vertsT  = (float4*)d_ws;
    h4*       vn      = (h4*)d_ws;                  // alias
    h4*       fn      = (h4*)(vertsT + (size_t)V * 8);
    h4*       vals    = fn;                         // alias
    Corner16* corners = (Corner16*)((char*)fn + (size_t)F * 8 * sizeof(h4));
    int*      hist    = (int*)(corners + (size_t)T * 4);  // (EB,NBUK)
    int*      tot     = hist + (size_t)EB * NBUK;   // NBUK
    int*      pairs   = tot + NBUK;                 // 3F

    const int BLK = 256;
    k1_pre<<<TRB + EB, BLK, 0, stream>>>(verts, vertsT, vi, hist);
    k2_fused<<<FNB + CPB + NBUK, BLK, 0, stream>>>(
        vi, vertsT, fn, idx_img, bary, vt, corners, hist, tot);
    k4_scatter<<<EB, BLK, 0, stream>>>(vi, hist, tot, pairs);
    k5_gather<<<NBUK, BLK, 0, stream>>>(pairs, tot, fn, vn);
    sample_points<<<((T / SQ) * 8 + BLK - 1) / BLK, BLK, 0, stream>>>(
        vn, corners, vals);
    gather_out<<<((V / VQ) * 8 + BLK - 1) / BLK, BLK, 0, stream>>>(
        vals, v2uv, out);
}